// Round 3
// baseline (385.162 us; speedup 1.0000x reference)
//
#include <hip/hip_runtime.h>
#include <stdint.h>

typedef __attribute__((ext_vector_type(8))) short bf16x8;
typedef __attribute__((ext_vector_type(4))) float f32x4;

__device__ __forceinline__ float bf2f(unsigned short b) {
  union { unsigned int u; float f; } c; c.u = ((unsigned int)b) << 16; return c.f;
}
__device__ __forceinline__ unsigned short f2bf(float f) {
  union { float f; unsigned int u; } c; c.f = f;
  unsigned int u = c.u;
  return (unsigned short)((u + 0x7fffu + ((u >> 16) & 1u)) >> 16);
}

__device__ __forceinline__ void gload_lds16(const void* g, void* l) {
  __builtin_amdgcn_global_load_lds((const __attribute__((address_space(1))) void*)g,
                                   (__attribute__((address_space(3))) void*)l,
                                   16, 0, 0);
}

// log2(e)/8 : fold score scaling + exp->exp2 conversion into q
#define QSCALE 0.18033688011112042f

// ---------------- converts / transposes ----------------

__global__ __launch_bounds__(256) void cvt_x(const float* __restrict__ in,
                                             unsigned short* __restrict__ out, int n4) {
  int i = blockIdx.x * 256 + threadIdx.x;
  if (i < n4) {
    float4 f = ((const float4*)in)[i];
    ushort4 o;
    o.x = f2bf(f.x); o.y = f2bf(f.y); o.z = f2bf(f.z); o.w = f2bf(f.w);
    ((ushort4*)out)[i] = o;
  }
}

// W [512][N] fp32 -> Wt [N][512] bf16, LDS-tiled (coalesced both sides).
__global__ __launch_bounds__(256)
void tw_cvt_t(const float* __restrict__ W, unsigned short* __restrict__ Wt, int N) {
  __shared__ unsigned short T[64][68];
  const int n0 = blockIdx.x * 64, k0 = blockIdx.y * 64;
  const int c = threadIdx.x & 15, r = threadIdx.x >> 4;
#pragma unroll
  for (int i = 0; i < 4; ++i) {
    float4 f = *(const float4*)&W[(size_t)(k0 + i * 16 + r) * N + n0 + c * 4];
    T[c * 4 + 0][i * 16 + r] = f2bf(f.x);
    T[c * 4 + 1][i * 16 + r] = f2bf(f.y);
    T[c * 4 + 2][i * 16 + r] = f2bf(f.z);
    T[c * 4 + 3][i * 16 + r] = f2bf(f.w);
  }
  __syncthreads();
#pragma unroll
  for (int i = 0; i < 4; ++i)
    *(ushort4*)&Wt[(size_t)(n0 + i * 16 + r) * 512 + k0 + c * 4] =
        *(const ushort4*)&T[i * 16 + r][c * 4];
}

// v [bh][4096][64] bf16 -> vt [bh][64][4096] bf16, LDS-tiled.
__global__ __launch_bounds__(256)
void vtr(const unsigned short* __restrict__ vsd, unsigned short* __restrict__ vt) {
  __shared__ unsigned short T[64][68];
  const int bh = blockIdx.y, s0 = blockIdx.x * 64;
  const int c = threadIdx.x & 15, r = threadIdx.x >> 4;
#pragma unroll
  for (int i = 0; i < 4; ++i) {
    ushort4 u = *(const ushort4*)&vsd[((size_t)bh * 4096 + s0 + i * 16 + r) * 64 + c * 4];
    T[c * 4 + 0][i * 16 + r] = u.x;
    T[c * 4 + 1][i * 16 + r] = u.y;
    T[c * 4 + 2][i * 16 + r] = u.z;
    T[c * 4 + 3][i * 16 + r] = u.w;
  }
  __syncthreads();
#pragma unroll
  for (int i = 0; i < 4; ++i)
    *(ushort4*)&vt[((size_t)bh * 64 + i * 16 + r) * 4096 + s0 + c * 4] =
        *(const ushort4*)&T[i * 16 + r][c * 4];
}

// ---------------- bf16 MFMA GEMM:  C = A * Bt^T + bias ----------------
// QKV==1: scatter into q (pre-scaled by QSCALE), k, v — all [bh][s][64] bf16.
// QKV==0: fp32 Cout.

template<int QKV>
__global__ __launch_bounds__(256)
void gemm_bt(const unsigned short* __restrict__ A, const unsigned short* __restrict__ Bt,
             const float* __restrict__ bias, float* __restrict__ Cout,
             unsigned short* __restrict__ qo, unsigned short* __restrict__ ko,
             unsigned short* __restrict__ vo, int M, int N, int K) {
  __shared__ unsigned short As[128 * 64];
  __shared__ unsigned short Bs[128 * 64];
  const int tid = threadIdx.x;
  const int wid = tid >> 6;
  const int lane = tid & 63;
  const int row0 = blockIdx.x * 128;
  const int col0 = blockIdx.y * 128;

  f32x4 acc[4][4];
#pragma unroll
  for (int m = 0; m < 4; ++m)
#pragma unroll
    for (int n = 0; n < 4; ++n)
      acc[m][n] = (f32x4){0.f, 0.f, 0.f, 0.f};

  const int wr = (wid >> 1) * 64;
  const int wc = (wid & 1) * 64;
  const int rw = lane & 15;
  const int nk = K >> 6;

  for (int kt = 0; kt < nk; ++kt) {
    const int k0 = kt << 6;
#pragma unroll
    for (int i = 0; i < 4; ++i) {
      int c = i * 256 + tid;
      int r = c >> 3, kq = (c & 7) << 3;
      gload_lds16(A + (size_t)(row0 + r) * K + k0 + kq, As + (size_t)(i * 256 + wid * 64) * 8);
    }
#pragma unroll
    for (int i = 0; i < 4; ++i) {
      int c = i * 256 + tid;
      int r = c >> 3, kq = (c & 7) << 3;
      gload_lds16(Bt + (size_t)(col0 + r) * K + k0 + kq, Bs + (size_t)(i * 256 + wid * 64) * 8);
    }
    __syncthreads();
#pragma unroll
    for (int ks = 0; ks < 2; ++ks) {
      const int kof = ks * 32 + (lane >> 4) * 8;
      bf16x8 af[4], bfr[4];
#pragma unroll
      for (int m = 0; m < 4; ++m)
        af[m] = *(const bf16x8*)&As[(wr + m * 16 + rw) * 64 + kof];
#pragma unroll
      for (int n = 0; n < 4; ++n)
        bfr[n] = *(const bf16x8*)&Bs[(wc + n * 16 + rw) * 64 + kof];
#pragma unroll
      for (int m = 0; m < 4; ++m)
#pragma unroll
        for (int n = 0; n < 4; ++n)
          acc[m][n] = __builtin_amdgcn_mfma_f32_16x16x32_bf16(af[m], bfr[n], acc[m][n], 0, 0, 0);
    }
    __syncthreads();
  }

  const int lr4 = (lane >> 4) * 4;
  const int lc = lane & 15;
#pragma unroll
  for (int m = 0; m < 4; ++m) {
#pragma unroll
    for (int n = 0; n < 4; ++n) {
      const int col = col0 + wc + n * 16 + lc;
      const float bb = bias[col];
      const int row = row0 + wr + m * 16 + lr4;
      if (QKV) {
        const int which = col >> 9;
        const int rem = col & 511, h = rem >> 6, d = rem & 63;
        const int b = row >> 12, s = row & 4095;
        const float scale = (which == 0) ? QSCALE : 1.0f;
        unsigned short* dst = (which == 0) ? qo : ((which == 1) ? ko : vo);
#pragma unroll
        for (int r2 = 0; r2 < 4; ++r2)
          dst[(((size_t)(b * 8 + h) * 4096 + (s + r2)) << 6) + d] =
              f2bf((acc[m][n][r2] + bb) * scale);
      } else {
#pragma unroll
        for (int r2 = 0; r2 < 4; ++r2)
          Cout[(size_t)(row + r2) * N + col] = acc[m][n][r2] + bb;
      }
    }
  }
}

// ---------------- MFMA flash attention (bf16, causal, log2-domain) -------
// grid (32, BH), 256 threads = 4 waves, one 128-row q-tile per block
// (p = 31-blockIdx.x so long causal blocks dispatch first). Wave owns 32 q
// rows; Q-frags hoisted to registers. K/V double-buffered in LDS (1 barrier
// per tile, stage-next-first). Softmax: defer-max fast path (no cross-lane
// ops unless row max grows > 8), per-lane partial l reduced at epilogue.

__global__ __launch_bounds__(256, 3)
void attn_mfma(const unsigned short* __restrict__ Qb, const unsigned short* __restrict__ Kb,
               const unsigned short* __restrict__ Vtb, unsigned short* __restrict__ Ob,
               const int* __restrict__ causal_p) {
  __shared__ unsigned short Ks[2][64 * 64];
  __shared__ unsigned short Vs[2][64 * 64];
  __shared__ unsigned short Ps[4][32 * 64];

  const int tid = threadIdx.x;
  const int wid = tid >> 6;
  const int lane = tid & 63;
  const int lx = lane & 15, ly = lane >> 4, l7 = lane & 7;
  const int p = 31 - blockIdx.x;
  const int bh = blockIdx.y;
  const int causal = *causal_p;
  const int qw = p * 128 + wid * 32;
  const size_t qkbase = (size_t)bh * 4096 * 64;
  const size_t vbase = (size_t)bh * 64 * 4096;

  // Q fragments from global (already scaled by QSCALE)
  bf16x8 qf[2][2];
#pragma unroll
  for (int rf = 0; rf < 2; ++rf)
#pragma unroll
    for (int ks = 0; ks < 2; ++ks)
      qf[rf][ks] =
          *(const bf16x8*)(Qb + qkbase + (size_t)(qw + rf * 16 + lx) * 64 + ks * 32 + ly * 8);

  f32x4 o[2][4];
  float mrow[2][4], lpart[2][4];
#pragma unroll
  for (int rf = 0; rf < 2; ++rf) {
#pragma unroll
    for (int df = 0; df < 4; ++df) o[rf][df] = (f32x4){0.f, 0.f, 0.f, 0.f};
#pragma unroll
    for (int r = 0; r < 4; ++r) { mrow[rf][r] = -1e30f; lpart[rf][r] = 0.f; }
  }

  const int ktmax = causal ? (2 * p + 1) : 63;

  // ---- prologue: stage tile 0 into buf 0 ----
#pragma unroll
  for (int pass = 0; pass < 2; ++pass) {
    int c = pass * 256 + tid;
    int r = c >> 3, ch = c & 7;
    gload_lds16(Kb + qkbase + (size_t)r * 64 + ((ch ^ (r & 7)) << 3),
                &Ks[0][(size_t)(pass * 256 + wid * 64) * 8]);
    gload_lds16(Vtb + vbase + (size_t)r * 4096 + ((ch ^ (r & 7)) << 3),
                &Vs[0][(size_t)(pass * 256 + wid * 64) * 8]);
  }
  __syncthreads();

  int cur = 0;
  for (int kt = 0; kt <= ktmax; ++kt) {
    if (kt < ktmax) {
      const int nx = kt + 1;
#pragma unroll
      for (int pass = 0; pass < 2; ++pass) {
        int c = pass * 256 + tid;
        int r = c >> 3, ch = c & 7;
        gload_lds16(Kb + qkbase + (size_t)(nx * 64 + r) * 64 + ((ch ^ (r & 7)) << 3),
                    &Ks[cur ^ 1][(size_t)(pass * 256 + wid * 64) * 8]);
        gload_lds16(Vtb + vbase + (size_t)r * 4096 + nx * 64 + ((ch ^ (r & 7)) << 3),
                    &Vs[cur ^ 1][(size_t)(pass * 256 + wid * 64) * 8]);
      }
    }

    const int ktb = kt * 64;
    if (!causal || ktb <= qw + 31) {
      // ---- QK^T ----
      f32x4 s[2][4];
#pragma unroll
      for (int rf = 0; rf < 2; ++rf)
#pragma unroll
        for (int cf = 0; cf < 4; ++cf) s[rf][cf] = (f32x4){0.f, 0.f, 0.f, 0.f};
#pragma unroll
      for (int ks = 0; ks < 2; ++ks) {
        const int kel = ((ks * 4 + ly) ^ l7) << 3;
        bf16x8 kf[4];
#pragma unroll
        for (int cf = 0; cf < 4; ++cf)
          kf[cf] = *(const bf16x8*)&Ks[cur][(cf * 16 + lx) * 64 + kel];
#pragma unroll
        for (int rf = 0; rf < 2; ++rf)
#pragma unroll
          for (int cf = 0; cf < 4; ++cf)
            s[rf][cf] = __builtin_amdgcn_mfma_f32_16x16x32_bf16(qf[rf][ks], kf[cf], s[rf][cf], 0, 0, 0);
      }

      // ---- mask + local max / threshold check ----
      const bool diag = causal && (ktb + 63 > qw);
      float tmx[2][4];
      bool ok = true;
#pragma unroll
      for (int rf = 0; rf < 2; ++rf) {
#pragma unroll
        for (int r = 0; r < 4; ++r) {
          if (diag) {
            const int qg = qw + rf * 16 + ly * 4 + r;
#pragma unroll
            for (int cf = 0; cf < 4; ++cf)
              if (ktb + cf * 16 + lx > qg) s[rf][cf][r] = -1e30f;
          }
          const float a0 = fmaxf(s[rf][0][r], s[rf][1][r]);
          const float a1 = fmaxf(s[rf][2][r], s[rf][3][r]);
          tmx[rf][r] = fmaxf(a0, a1);
          ok = ok && (tmx[rf][r] <= mrow[rf][r] + 8.f);
        }
      }

      if (__all(ok)) {
        // fast path: m unchanged, no cross-lane ops, no O rescale
#pragma unroll
        for (int rf = 0; rf < 2; ++rf) {
#pragma unroll
          for (int r = 0; r < 4; ++r) {
            const float mo = mrow[rf][r];
            const int ql = rf * 16 + ly * 4 + r;
            const int swz = (ql & 7) << 3;
            float lp = 0.f;
#pragma unroll
            for (int cf = 0; cf < 4; ++cf) {
              const float pv = __builtin_amdgcn_exp2f(s[rf][cf][r] - mo);
              lp += pv;
              Ps[wid][ql * 64 + ((cf * 16 + lx) ^ swz)] = f2bf(pv);
            }
            lpart[rf][r] += lp;
          }
        }
      } else {
        // slow path: full max reduce + rescale
#pragma unroll
        for (int rf = 0; rf < 2; ++rf) {
#pragma unroll
          for (int r = 0; r < 4; ++r) {
            float tm = tmx[rf][r];
            tm = fmaxf(tm, __shfl_xor(tm, 1));
            tm = fmaxf(tm, __shfl_xor(tm, 2));
            tm = fmaxf(tm, __shfl_xor(tm, 4));
            tm = fmaxf(tm, __shfl_xor(tm, 8));
            const float mo = mrow[rf][r];
            const float mn = fmaxf(mo, tm);
            const float scl = __builtin_amdgcn_exp2f(mo - mn);
            const int ql = rf * 16 + ly * 4 + r;
            const int swz = (ql & 7) << 3;
            float lp = 0.f;
#pragma unroll
            for (int cf = 0; cf < 4; ++cf) {
              const float pv = __builtin_amdgcn_exp2f(s[rf][cf][r] - mn);
              lp += pv;
              Ps[wid][ql * 64 + ((cf * 16 + lx) ^ swz)] = f2bf(pv);
            }
            lpart[rf][r] = lpart[rf][r] * scl + lp;
            mrow[rf][r] = mn;
#pragma unroll
            for (int df = 0; df < 4; ++df) o[rf][df][r] *= scl;
          }
        }
      }

      // ---- PV ----
#pragma unroll
      for (int ks = 0; ks < 2; ++ks) {
        const int kel = ((ks * 4 + ly) ^ l7) << 3;
        bf16x8 pa[2], vf[4];
#pragma unroll
        for (int rf = 0; rf < 2; ++rf)
          pa[rf] = *(const bf16x8*)&Ps[wid][(rf * 16 + lx) * 64 + kel];
#pragma unroll
        for (int df = 0; df < 4; ++df)
          vf[df] = *(const bf16x8*)&Vs[cur][(df * 16 + lx) * 64 + kel];
#pragma unroll
        for (int rf = 0; rf < 2; ++rf)
#pragma unroll
          for (int df = 0; df < 4; ++df)
            o[rf][df] = __builtin_amdgcn_mfma_f32_16x16x32_bf16(pa[rf], vf[df], o[rf][df], 0, 0, 0);
      }
    }
    __syncthreads();
    cur ^= 1;
  }

  // ---- epilogue: reduce per-lane l, normalize, write ----
  const int b = bh >> 3, h = bh & 7;
#pragma unroll
  for (int rf = 0; rf < 2; ++rf) {
#pragma unroll
    for (int r = 0; r < 4; ++r) {
      float l = lpart[rf][r];
      l += __shfl_xor(l, 1);
      l += __shfl_xor(l, 2);
      l += __shfl_xor(l, 4);
      l += __shfl_xor(l, 8);
      const float inv = 1.0f / l;
      const int row = b * 4096 + qw + rf * 16 + ly * 4 + r;
#pragma unroll
      for (int df = 0; df < 4; ++df)
        Ob[(size_t)row * 512 + h * 64 + df * 16 + lx] = f2bf(o[rf][df][r] * inv);
    }
  }
}

// ---------------- launch ----------------

extern "C" void kernel_launch(void* const* d_in, const int* in_sizes, int n_in,
                              void* d_out, int out_size, void* d_ws, size_t ws_size,
                              hipStream_t stream) {
  const float* x     = (const float*)d_in[0];
  const float* W_in  = (const float*)d_in[1];
  const float* b_in  = (const float*)d_in[2];
  const float* W_out = (const float*)d_in[3];
  const float* b_out = (const float*)d_in[4];
  const int* causal  = (const int*)d_in[5];
  float* out = (float*)d_out;

  unsigned short* xb   = (unsigned short*)d_ws;       // 8192*512 bf16 x; later attn out
  unsigned short* wint = xb + 4194304;                // 1536*512
  unsigned short* wout = wint + 786432;               // 512*512
  unsigned short* qb   = wout + 262144;               // [16][4096][64]
  unsigned short* kb   = qb + 4194304;                // [16][4096][64]
  unsigned short* vt   = kb + 4194304;                // [16][64][4096]
  unsigned short* vsd  = (unsigned short*)d_out;      // scratch [16][4096][64] (8.4MB<16.8MB)

  cvt_x<<<4096, 256, 0, stream>>>(x, xb, 1048576);
  tw_cvt_t<<<dim3(24, 8), 256, 0, stream>>>(W_in, wint, 1536);
  tw_cvt_t<<<dim3(8, 8), 256, 0, stream>>>(W_out, wout, 512);

  gemm_bt<1><<<dim3(64, 12), 256, 0, stream>>>(xb, wint, b_in, nullptr, qb, kb, vsd,
                                               8192, 1536, 512);

  vtr<<<dim3(64, 16), 256, 0, stream>>>(vsd, vt);

  attn_mfma<<<dim3(32, 16), 256, 0, stream>>>(qb, kb, vt, xb, causal);

  gemm_bt<0><<<dim3(64, 4), 256, 0, stream>>>(xb, wout, b_out, out, nullptr, nullptr, nullptr,
                                              8192, 512, 512);
}